// Round 9
// baseline (413.435 us; speedup 1.0000x reference)
//
#include <hip/hip_runtime.h>

typedef float f4v __attribute__((ext_vector_type(4)));
typedef _Float16 h8 __attribute__((ext_vector_type(8)));
typedef _Float16 h4 __attribute__((ext_vector_type(4)));

// Problem constants
// C=192, NH=8, DH=24, window 6x8x8 -> N=384 tokens, D/H/W = 24/64/64 -> 256 windows
// shift (3,4,4). Spatial stride per channel = 24*64*64 = 98304.
// Staging layout (f16): [head][win][n][24]  -> slab (head,win) = 384*24 = 9216 elems.

__device__ __forceinline__ float fast_exp2(float x) {
#if __has_builtin(__builtin_amdgcn_exp2f)
    return __builtin_amdgcn_exp2f(x);
#else
    return exp2f(x);
#endif
}
__device__ __forceinline__ float fast_rcp(float x) {
#if __has_builtin(__builtin_amdgcn_rcpf)
    return __builtin_amdgcn_rcpf(x);
#else
    return 1.0f / x;
#endif
}

// ---------------------------------------------------------------------------
// Kernel 1: transpose + roll + window-partition + LayerNorm -> f16 staging
// ---------------------------------------------------------------------------
__global__ __launch_bounds__(256) void ln_stage_kernel(
    const float* __restrict__ q, const float* __restrict__ k, const float* __restrict__ v,
    const float* __restrict__ nqw, const float* __restrict__ nqb,
    const float* __restrict__ nkw, const float* __restrict__ nkb,
    _Float16* __restrict__ Qs, _Float16* __restrict__ Ks, _Float16* __restrict__ Vs)
{
    const int tid = threadIdx.x;
    const int bid = blockIdx.x;      // d*64 + h
    const int tensor = blockIdx.y;   // 0=q, 1=k, 2=v
    const int d = bid >> 6;
    const int h = bid & 63;

    const float* src = (tensor == 0) ? q : (tensor == 1) ? k : v;
    const float* gam = (tensor == 0) ? nqw : nkw;
    const float* bet = (tensor == 0) ? nqb : nkb;
    _Float16* dst = (tensor == 0) ? Qs : (tensor == 1) ? Ks : Vs;
    // fold softmax scale (1/sqrt(24)) and log2(e) into Q so scores are in exp2 domain
    const float scale = (tensor == 0) ? (0.20412414523193154f * 1.44269504088896340f) : 1.0f;

    __shared__ __attribute__((aligned(16))) float tile[192][64];
    __shared__ float psum[4][64];
    __shared__ float psq[4][64];
    __shared__ float smean[64];
    __shared__ float srstd[64];
    __shared__ float sgam[192];
    __shared__ float sbet[192];

    if (tid < 192) { sgam[tid] = gam[tid]; sbet[tid] = bet[tid]; }

    // coalesced load of 192 channels x 64 w (256B per row)
    {
        const float* base = src + (size_t)d * 4096 + (size_t)h * 64;
        const int c0 = tid >> 4;
        const int col = (tid & 15) << 2;
        #pragma unroll
        for (int r = 0; r < 12; ++r) {
            int c = r * 16 + c0;
            f4v x = *(const f4v*)(base + (size_t)c * 98304 + col);
            *(f4v*)&tile[c][col] = x;
        }
    }
    __syncthreads();

    // per-token (per-w-column) mean / var
    {
        const int wcol = tid & 63;
        const int p = tid >> 6;
        float s = 0.f, ss = 0.f;
        #pragma unroll
        for (int i = 0; i < 48; ++i) {
            float x = tile[p * 48 + i][wcol];
            s += x; ss += x * x;
        }
        psum[p][wcol] = s; psq[p][wcol] = ss;
    }
    __syncthreads();
    if (tid < 64) {
        float S  = psum[0][tid] + psum[1][tid] + psum[2][tid] + psum[3][tid];
        float SS = psq[0][tid] + psq[1][tid] + psq[2][tid] + psq[3][tid];
        float mean = S * (1.0f / 192.0f);
        float var = SS * (1.0f / 192.0f) - mean * mean;
        smean[tid] = mean;
        srstd[tid] = rsqrtf(var + 1e-5f);
    }
    __syncthreads();

    // normalize + write f16 staging, head-major: [head][win][n][24]
    {
        const int wpos = tid >> 2;   // 0..63 source w
        const int p = tid & 3;       // channel quarter = heads 2p, 2p+1
        const float mean = smean[wpos];
        const float rstd = srstd[wpos];
        int d_r = d + 21; if (d_r >= 24) d_r -= 24;
        int h_r = h + 60; if (h_r >= 64) h_r -= 64;
        int w_r = wpos + 60; if (w_r >= 64) w_r -= 64;
        const int wi = d_r / 6, td = d_r - wi * 6;
        const int hi = h_r >> 3, th = h_r & 7;
        const int wj = w_r >> 3, tw = w_r & 7;
        const int win = (wi * 8 + hi) * 8 + wj;
        const int n = (td * 8 + th) * 8 + tw;
        #pragma unroll
        for (int hh2 = 0; hh2 < 2; ++hh2) {
            const int head = p * 2 + hh2;
            _Float16* outp = dst + (size_t)(head * 256 + win) * 9216 + n * 24;
            #pragma unroll
            for (int cc = 0; cc < 3; ++cc) {
                const int c = head * 24 + cc * 8;
                h8 hv;
                #pragma unroll
                for (int j = 0; j < 8; ++j) {
                    float x = (tile[c + j][wpos] - mean) * rstd * sgam[c + j] + sbet[c + j];
                    hv[j] = (_Float16)(x * scale);
                }
                *(h8*)(outp + cc * 8) = hv;
            }
        }
    }
}

// ---------------------------------------------------------------------------
// Kernel 2: proj_w f32 -> f16
// ---------------------------------------------------------------------------
__global__ __launch_bounds__(256) void wconv_kernel(const float* __restrict__ w,
                                                    _Float16* __restrict__ wb)
{
    int i = blockIdx.x * 256 + threadIdx.x;
    if (i < 192 * 192) wb[i] = (_Float16)w[i];
}

// ---------------------------------------------------------------------------
// Kernel 3: windowed attention, one block per (window, head). 4 waves.
// NO-MAX softmax: scores are bounded (LN'd inputs, scale folded), so
// p = exp2(s - 6) with the -6 folded into the QK MFMA C-init (shift-invariant,
// zero VALU). This fuses QK -> exp -> PV into ONE mt loop (no phase barrier,
// no s[24] live array, no fmax chain/swizzles). o accumulators split into
// a/b banks to break the 24-deep MFMA dependency chain.
// VGPR drops ~96 -> (256,4) safe; LDS 40960B x 4 = exactly 160KiB -> 4 blk/CU.
// Epilogue + fences identical to the proven round-4 structure.
// ---------------------------------------------------------------------------
__global__ __launch_bounds__(256, 4) void attn_kernel(
    const _Float16* __restrict__ Qs, const _Float16* __restrict__ Ks,
    const _Float16* __restrict__ Vs, _Float16* __restrict__ AOs)
{
    const int win = blockIdx.x;
    const int head = blockIdx.y;
    const int tid = threadIdx.x;
    const int lane = tid & 63;
    const int wid = tid >> 6;
    const int l15 = lane & 15;
    const int g = lane >> 4;

    __shared__ __attribute__((aligned(16))) _Float16 Kh[384 * 24 + 8]; // [token][24] + zero tail
    __shared__ __attribute__((aligned(16))) _Float16 Vt[24 * 388];     // [dh][token pad388]
    __shared__ __attribute__((aligned(16))) _Float16 Ob[4][16 * 24];   // per-wave output tile
    __shared__ __attribute__((aligned(4)))  unsigned char rid[384];

    const int wi = win >> 6, hi = (win >> 3) & 7, wj = win & 7;
    const bool mixed = (wi == 3) || (hi == 7) || (wj == 7);

    const size_t slab = (size_t)(head * 256 + win) * 9216;
    const _Float16* Kw = Ks + slab;
    const _Float16* Vw = Vs + slab;
    const _Float16* Qw = Qs + slab;
    _Float16* AOw = AOs + slab;

    // ---- hoist all 6 Q fragments (issued before staging; overlap) ----
    // g==3 chunk MUST be exactly zero (matching K chunk is next-row data).
    h8 qreg[6];
    #pragma unroll
    for (int qt = 0; qt < 6; ++qt) {
        h8 z = {};
        qreg[qt] = z;
        if (g < 3)
            qreg[qt] = *(const h8*)(Qw + (size_t)(wid * 96 + qt * 16 + l15) * 24 + g * 8);
    }

    // ---- stage K (flat copy) and V^T (transpose), region ids ----
    {
        const h8* K8 = (const h8*)Kw;
        const h8* V8 = (const h8*)Vw;
        #pragma unroll
        for (int it = 0; it < 9; ++it) {
            int idx = it * 256 + tid;        // 0..2303 ; 0..1151 = K, 1152.. = V
            if (idx < 1152) {
                *(h8*)(Kh + idx * 8) = K8[idx];
            } else {
                int i = idx - 1152;          // flat h8 index in V slab
                int n = i / 3;               // token
                int ch = i - n * 3;          // 8-dh chunk
                h8 vv = V8[i];
                #pragma unroll
                for (int j = 0; j < 8; ++j) Vt[(ch * 8 + j) * 388 + n] = vv[j];
            }
        }
        if (tid == 0) {  // zero the 8-elem overhang read by (mt=23,l15=15,g=3)
            const h8 z8 = {};
            *(h8*)(Kh + 384 * 24) = z8;
        }
        for (int n = tid; n < 384; n += 256) {
            int twn = n & 7, thn = (n >> 3) & 7, tdn = n >> 6;
            int rd = (wi == 3) ? (tdn < 3 ? 1 : 2) : 0;
            int rh = (hi == 7) ? (thn < 4 ? 1 : 2) : 0;
            int rw = (wj == 7) ? (twn < 4 ? 1 : 2) : 0;
            rid[n] = (unsigned char)(rd * 9 + rh * 3 + rw);
        }
    }
    __syncthreads();

    const int v1row = 16 + (l15 & 7);   // lanes 8-15 duplicate rows 16-23 (discarded cols)

    for (int qt = 0; qt < 6; ++qt) {
        const int q0 = wid * 96 + qt * 16;
        const h8 qf = qreg[qt];
        const unsigned int rq = rid[q0 + l15];

        float sum = 0.f;
        f4v o0a = {}, o0b = {}, o1a = {}, o1b = {};
        #pragma unroll
        for (int mt = 0; mt < 24; ++mt) {
            h8 kf = *(const h8*)(Kh + (16 * mt + l15) * 24 + g * 8);
            const f4v cinit = {-6.f, -6.f, -6.f, -6.f};
            f4v s4 = __builtin_amdgcn_mfma_f32_16x16x32_f16(kf, qf, cinit, 0, 0, 0);
            // lane (l15,g): s4[j] = S[q=q0+l15][k=16mt+4g+j] - 6
            if (mixed) {
                unsigned int r4 = *(const unsigned int*)(rid + 16 * mt + 4 * g);
                #pragma unroll
                for (int j = 0; j < 4; ++j) {
                    if (((r4 >> (8 * j)) & 255u) != rq) s4[j] = -1e30f;
                }
            }
            float p0 = fast_exp2(s4[0]);
            float p1 = fast_exp2(s4[1]);
            float p2 = fast_exp2(s4[2]);
            float p3 = fast_exp2(s4[3]);
            sum += (p0 + p1) + (p2 + p3);
            h4 pa;
            pa[0] = (_Float16)p0; pa[1] = (_Float16)p1;
            pa[2] = (_Float16)p2; pa[3] = (_Float16)p3;
            h4 v0 = *(const h4*)(Vt + l15 * 388 + 16 * mt + 4 * g);
            h4 v1 = *(const h4*)(Vt + v1row * 388 + 16 * mt + 4 * g);
            if (mt & 1) {
                o0b = __builtin_amdgcn_mfma_f32_16x16x16f16(pa, v0, o0b, 0, 0, 0);
                o1b = __builtin_amdgcn_mfma_f32_16x16x16f16(pa, v1, o1b, 0, 0, 0);
            } else {
                o0a = __builtin_amdgcn_mfma_f32_16x16x16f16(pa, v0, o0a, 0, 0, 0);
                o1a = __builtin_amdgcn_mfma_f32_16x16x16f16(pa, v1, o1a, 0, 0, 0);
            }
        }
        f4v o0 = o0a + o0b;
        f4v o1 = o1a + o1b;
        sum += __shfl_xor(sum, 16);
        sum += __shfl_xor(sum, 32);
        // lane (l15,g): sum = row-sum for q=q0+l15

        // normalize -> per-wave LDS tile (wave-private; DS ops are in-order
        // per wave, so only compiler fences are needed, no barrier)
        _Float16* Op = Ob[wid];
        #pragma unroll
        for (int j = 0; j < 4; ++j) {
            float sj = __shfl(sum, 4 * g + j);
            float inv = fast_rcp(sj);
            const int r16 = 4 * g + j;
            Op[r16 * 24 + l15] = (_Float16)(o0[j] * inv);
            if (l15 < 8) Op[r16 * 24 + 16 + l15] = (_Float16)(o1[j] * inv);
        }
        asm volatile("s_waitcnt lgkmcnt(0)" ::: "memory");
        // coalesced 768B burst: 48 lanes x 16B contiguous
        if (lane < 48) {
            h8 ov = *(const h8*)(Op + lane * 8);
            *(h8*)(AOw + (size_t)q0 * 24 + lane * 8) = ov;
        }
        asm volatile("" ::: "memory");  // WAR: pin next-qt Ob writes after this read
    }
}

// ---------------------------------------------------------------------------
// Kernel 4: projection (X @ W^T + b) + window-reverse + roll-back + transpose
// block = half a window (192 tokens), 4 waves x 48 tokens.
// ---------------------------------------------------------------------------
__global__ __launch_bounds__(256) void proj_kernel(
    const _Float16* __restrict__ AOs, const _Float16* __restrict__ Wb,
    const float* __restrict__ bias, float* __restrict__ out)
{
    const int bid = blockIdx.x;
    const int win = bid >> 1, half = bid & 1;
    const int tid = threadIdx.x;
    const int lane = tid & 63, wid = tid >> 6;
    const int l15 = lane & 15, g = lane >> 4;
    const int wi = win >> 6, hi = (win >> 3) & 7, wj = win & 7;

    __shared__ __attribute__((aligned(16))) float tileT[4][192 * 20];
    float* Tw = tileT[wid];

    // per-lane fragment -> (head, sub-chunk) decomposition for m = kk*4+g
    int hdk[6], sbk[6];
    #pragma unroll
    for (int kk = 0; kk < 6; ++kk) {
        int mm = kk * 4 + g;
        hdk[kk] = mm / 3;
        sbk[kk] = mm - 3 * hdk[kk];
    }

    for (int mi = 0; mi < 3; ++mi) {
        __syncthreads();   // WAR: previous epilogue reads done before overwrite
        const int tb = half * 192 + wid * 48 + mi * 16;
        f4v acc[12];
        const f4v zz = {};
        #pragma unroll
        for (int n = 0; n < 12; ++n) acc[n] = zz;
        #pragma unroll
        for (int kk = 0; kk < 6; ++kk) {
            h8 af = *(const h8*)(AOs + (size_t)(hdk[kk] * 256 + win) * 9216
                                     + (size_t)(tb + l15) * 24 + sbk[kk] * 8);
            #pragma unroll
            for (int n = 0; n < 12; ++n) {
                h8 bf = *(const h8*)(Wb + (size_t)(n * 16 + l15) * 192 + kk * 32 + g * 8);
                acc[n] = __builtin_amdgcn_mfma_f32_16x16x32_f16(af, bf, acc[n], 0, 0, 0);
            }
        }
        // bias + transpose through LDS ([c][token16] pad20 -> conflict-free)
        #pragma unroll
        for (int n = 0; n < 12; ++n) {
            float b = bias[n * 16 + l15];
            f4v vv = acc[n];
            vv[0] += b; vv[1] += b; vv[2] += b; vv[3] += b;
            *(f4v*)(Tw + (n * 16 + l15) * 20 + g * 4) = vv;
        }
        __syncthreads();   // make per-wave tile visible across lanes

        // each lane owns one token (i = l15), c = rr*4 + g -> 32B-coalesced stores
        const int i = l15;
        const int nn = tb + i;
        const int twn = nn & 7, thn = (nn >> 3) & 7, tdn = nn >> 6;
        int dd = wi * 6 + tdn + 3; if (dd >= 24) dd -= 24;
        int hh = hi * 8 + thn + 4; if (hh >= 64) hh -= 64;
        int ww = wj * 8 + twn + 4; if (ww >= 64) ww -= 64;
        const size_t sp = (size_t)dd * 4096 + hh * 64 + ww;
        #pragma unroll
        for (int rr = 0; rr < 48; ++rr) {
            const int c = rr * 4 + g;
            out[(size_t)c * 98304 + sp] = Tw[c * 20 + i];
        }
    }
}

// ---------------------------------------------------------------------------
extern "C" void kernel_launch(void* const* d_in, const int* in_sizes, int n_in,
                              void* d_out, int out_size, void* d_ws, size_t ws_size,
                              hipStream_t stream) {
    const float* q_map = (const float*)d_in[0];
    const float* k_map = (const float*)d_in[1];
    const float* v_map = (const float*)d_in[2];
    const float* nqw = (const float*)d_in[3];
    const float* nqb = (const float*)d_in[4];
    const float* nkw = (const float*)d_in[5];
    const float* nkb = (const float*)d_in[6];
    const float* pw = (const float*)d_in[7];
    const float* pb = (const float*)d_in[8];
    float* out = (float*)d_out;

    // workspace layout (f16): Qs, Ks, Vs, AOs each 8*256*384*24 = 18,874,368 elems
    _Float16* ws = (_Float16*)d_ws;
    const size_t BUF = (size_t)8 * 256 * 384 * 24;
    _Float16* Qs = ws;
    _Float16* Ks = ws + BUF;
    _Float16* Vs = ws + 2 * BUF;
    _Float16* AOs = ws + 3 * BUF;
    _Float16* Wb = ws + 4 * BUF;   // + 73728 B, total ~151 MB

    ln_stage_kernel<<<dim3(1536, 3), 256, 0, stream>>>(q_map, k_map, v_map,
                                                       nqw, nqb, nkw, nkb, Qs, Ks, Vs);
    wconv_kernel<<<144, 256, 0, stream>>>(pw, Wb);
    attn_kernel<<<dim3(256, 8), 256, 0, stream>>>(Qs, Ks, Vs, AOs);
    proj_kernel<<<512, 256, 0, stream>>>(AOs, Wb, pb, out);
}

// Round 10
// 366.362 us; speedup vs baseline: 1.1285x; 1.1285x over previous
//
#include <hip/hip_runtime.h>

typedef float f4v __attribute__((ext_vector_type(4)));
typedef _Float16 h8 __attribute__((ext_vector_type(8)));
typedef _Float16 h4 __attribute__((ext_vector_type(4)));

// Problem constants
// C=192, NH=8, DH=24, window 6x8x8 -> N=384 tokens, D/H/W = 24/64/64 -> 256 windows
// shift (3,4,4). Spatial stride per channel = 24*64*64 = 98304.
// Staging layout (f16): [head][win][n][24]  -> slab (head,win) = 384*24 = 9216 elems.

__device__ __forceinline__ float fast_exp2(float x) {
#if __has_builtin(__builtin_amdgcn_exp2f)
    return __builtin_amdgcn_exp2f(x);
#else
    return exp2f(x);
#endif
}
__device__ __forceinline__ float fast_rcp(float x) {
#if __has_builtin(__builtin_amdgcn_rcpf)
    return __builtin_amdgcn_rcpf(x);
#else
    return 1.0f / x;
#endif
}

// ---------------------------------------------------------------------------
// Kernel 1: transpose + roll + window-partition + LayerNorm -> f16 staging
// ---------------------------------------------------------------------------
__global__ __launch_bounds__(256) void ln_stage_kernel(
    const float* __restrict__ q, const float* __restrict__ k, const float* __restrict__ v,
    const float* __restrict__ nqw, const float* __restrict__ nqb,
    const float* __restrict__ nkw, const float* __restrict__ nkb,
    _Float16* __restrict__ Qs, _Float16* __restrict__ Ks, _Float16* __restrict__ Vs)
{
    const int tid = threadIdx.x;
    const int bid = blockIdx.x;      // d*64 + h
    const int tensor = blockIdx.y;   // 0=q, 1=k, 2=v
    const int d = bid >> 6;
    const int h = bid & 63;

    const float* src = (tensor == 0) ? q : (tensor == 1) ? k : v;
    const float* gam = (tensor == 0) ? nqw : nkw;
    const float* bet = (tensor == 0) ? nqb : nkb;
    _Float16* dst = (tensor == 0) ? Qs : (tensor == 1) ? Ks : Vs;
    // fold softmax scale (1/sqrt(24)) and log2(e) into Q so scores are in exp2 domain
    const float scale = (tensor == 0) ? (0.20412414523193154f * 1.44269504088896340f) : 1.0f;

    __shared__ __attribute__((aligned(16))) float tile[192][64];
    __shared__ float psum[4][64];
    __shared__ float psq[4][64];
    __shared__ float smean[64];
    __shared__ float srstd[64];
    __shared__ float sgam[192];
    __shared__ float sbet[192];

    if (tid < 192) { sgam[tid] = gam[tid]; sbet[tid] = bet[tid]; }

    // coalesced load of 192 channels x 64 w (256B per row)
    {
        const float* base = src + (size_t)d * 4096 + (size_t)h * 64;
        const int c0 = tid >> 4;
        const int col = (tid & 15) << 2;
        #pragma unroll
        for (int r = 0; r < 12; ++r) {
            int c = r * 16 + c0;
            f4v x = *(const f4v*)(base + (size_t)c * 98304 + col);
            *(f4v*)&tile[c][col] = x;
        }
    }
    __syncthreads();

    // per-token (per-w-column) mean / var
    {
        const int wcol = tid & 63;
        const int p = tid >> 6;
        float s = 0.f, ss = 0.f;
        #pragma unroll
        for (int i = 0; i < 48; ++i) {
            float x = tile[p * 48 + i][wcol];
            s += x; ss += x * x;
        }
        psum[p][wcol] = s; psq[p][wcol] = ss;
    }
    __syncthreads();
    if (tid < 64) {
        float S  = psum[0][tid] + psum[1][tid] + psum[2][tid] + psum[3][tid];
        float SS = psq[0][tid] + psq[1][tid] + psq[2][tid] + psq[3][tid];
        float mean = S * (1.0f / 192.0f);
        float var = SS * (1.0f / 192.0f) - mean * mean;
        smean[tid] = mean;
        srstd[tid] = rsqrtf(var + 1e-5f);
    }
    __syncthreads();

    // normalize + write f16 staging, head-major: [head][win][n][24]
    {
        const int wpos = tid >> 2;   // 0..63 source w
        const int p = tid & 3;       // channel quarter = heads 2p, 2p+1
        const float mean = smean[wpos];
        const float rstd = srstd[wpos];
        int d_r = d + 21; if (d_r >= 24) d_r -= 24;
        int h_r = h + 60; if (h_r >= 64) h_r -= 64;
        int w_r = wpos + 60; if (w_r >= 64) w_r -= 64;
        const int wi = d_r / 6, td = d_r - wi * 6;
        const int hi = h_r >> 3, th = h_r & 7;
        const int wj = w_r >> 3, tw = w_r & 7;
        const int win = (wi * 8 + hi) * 8 + wj;
        const int n = (td * 8 + th) * 8 + tw;
        #pragma unroll
        for (int hh2 = 0; hh2 < 2; ++hh2) {
            const int head = p * 2 + hh2;
            _Float16* outp = dst + (size_t)(head * 256 + win) * 9216 + n * 24;
            #pragma unroll
            for (int cc = 0; cc < 3; ++cc) {
                const int c = head * 24 + cc * 8;
                h8 hv;
                #pragma unroll
                for (int j = 0; j < 8; ++j) {
                    float x = (tile[c + j][wpos] - mean) * rstd * sgam[c + j] + sbet[c + j];
                    hv[j] = (_Float16)(x * scale);
                }
                *(h8*)(outp + cc * 8) = hv;
            }
        }
    }
}

// ---------------------------------------------------------------------------
// Kernel 2: proj_w f32 -> f16
// ---------------------------------------------------------------------------
__global__ __launch_bounds__(256) void wconv_kernel(const float* __restrict__ w,
                                                    _Float16* __restrict__ wb)
{
    int i = blockIdx.x * 256 + threadIdx.x;
    if (i < 192 * 192) wb[i] = (_Float16)w[i];
}

// ---------------------------------------------------------------------------
// Kernel 3: windowed attention, one block per (window, head). 4 waves.
// NO-MAX softmax: scores are bounded (LN'd inputs, scale folded), so
// p = exp2(s - 6) with the -6 folded into the QK MFMA C-init (shift-invariant,
// zero VALU). QK -> exp -> PV fused in ONE mt loop; o accumulators split into
// a/b banks to break the 24-deep MFMA chain.
// __launch_bounds__(256,3): (256,4) forces a 64-VGPR allocation -> scratch
// spills (FETCH 327MB, WRITE 388MB, +44us) — confirmed twice (r5, r9).
// ~100 live VGPRs need the 170 cap; 3 blocks/CU is the ceiling here.
// ---------------------------------------------------------------------------
__global__ __launch_bounds__(256, 3) void attn_kernel(
    const _Float16* __restrict__ Qs, const _Float16* __restrict__ Ks,
    const _Float16* __restrict__ Vs, _Float16* __restrict__ AOs)
{
    const int win = blockIdx.x;
    const int head = blockIdx.y;
    const int tid = threadIdx.x;
    const int lane = tid & 63;
    const int wid = tid >> 6;
    const int l15 = lane & 15;
    const int g = lane >> 4;

    __shared__ __attribute__((aligned(16))) _Float16 Kh[384 * 24 + 8]; // [token][24] + zero tail
    __shared__ __attribute__((aligned(16))) _Float16 Vt[24 * 388];     // [dh][token pad388]
    __shared__ __attribute__((aligned(16))) _Float16 Ob[4][16 * 24];   // per-wave output tile
    __shared__ __attribute__((aligned(4)))  unsigned char rid[384];

    const int wi = win >> 6, hi = (win >> 3) & 7, wj = win & 7;
    const bool mixed = (wi == 3) || (hi == 7) || (wj == 7);

    const size_t slab = (size_t)(head * 256 + win) * 9216;
    const _Float16* Kw = Ks + slab;
    const _Float16* Vw = Vs + slab;
    const _Float16* Qw = Qs + slab;
    _Float16* AOw = AOs + slab;

    // ---- hoist all 6 Q fragments (issued before staging; overlap) ----
    // g==3 chunk MUST be exactly zero (matching K chunk is next-row data).
    h8 qreg[6];
    #pragma unroll
    for (int qt = 0; qt < 6; ++qt) {
        h8 z = {};
        qreg[qt] = z;
        if (g < 3)
            qreg[qt] = *(const h8*)(Qw + (size_t)(wid * 96 + qt * 16 + l15) * 24 + g * 8);
    }

    // ---- stage K (flat copy) and V^T (transpose), region ids ----
    {
        const h8* K8 = (const h8*)Kw;
        const h8* V8 = (const h8*)Vw;
        #pragma unroll
        for (int it = 0; it < 9; ++it) {
            int idx = it * 256 + tid;        // 0..2303 ; 0..1151 = K, 1152.. = V
            if (idx < 1152) {
                *(h8*)(Kh + idx * 8) = K8[idx];
            } else {
                int i = idx - 1152;          // flat h8 index in V slab
                int n = i / 3;               // token
                int ch = i - n * 3;          // 8-dh chunk
                h8 vv = V8[i];
                #pragma unroll
                for (int j = 0; j < 8; ++j) Vt[(ch * 8 + j) * 388 + n] = vv[j];
            }
        }
        if (tid == 0) {  // zero the 8-elem overhang read by (mt=23,l15=15,g=3)
            const h8 z8 = {};
            *(h8*)(Kh + 384 * 24) = z8;
        }
        for (int n = tid; n < 384; n += 256) {
            int twn = n & 7, thn = (n >> 3) & 7, tdn = n >> 6;
            int rd = (wi == 3) ? (tdn < 3 ? 1 : 2) : 0;
            int rh = (hi == 7) ? (thn < 4 ? 1 : 2) : 0;
            int rw = (wj == 7) ? (twn < 4 ? 1 : 2) : 0;
            rid[n] = (unsigned char)(rd * 9 + rh * 3 + rw);
        }
    }
    __syncthreads();

    const int v1row = 16 + (l15 & 7);   // lanes 8-15 duplicate rows 16-23 (discarded cols)

    for (int qt = 0; qt < 6; ++qt) {
        const int q0 = wid * 96 + qt * 16;
        const h8 qf = qreg[qt];
        const unsigned int rq = rid[q0 + l15];

        float sum = 0.f;
        f4v o0a = {}, o0b = {}, o1a = {}, o1b = {};
        #pragma unroll
        for (int mt = 0; mt < 24; ++mt) {
            h8 kf = *(const h8*)(Kh + (16 * mt + l15) * 24 + g * 8);
            const f4v cinit = {-6.f, -6.f, -6.f, -6.f};
            f4v s4 = __builtin_amdgcn_mfma_f32_16x16x32_f16(kf, qf, cinit, 0, 0, 0);
            // lane (l15,g): s4[j] = S[q=q0+l15][k=16mt+4g+j] - 6
            if (mixed) {
                unsigned int r4 = *(const unsigned int*)(rid + 16 * mt + 4 * g);
                #pragma unroll
                for (int j = 0; j < 4; ++j) {
                    if (((r4 >> (8 * j)) & 255u) != rq) s4[j] = -1e30f;
                }
            }
            float p0 = fast_exp2(s4[0]);
            float p1 = fast_exp2(s4[1]);
            float p2 = fast_exp2(s4[2]);
            float p3 = fast_exp2(s4[3]);
            sum += (p0 + p1) + (p2 + p3);
            h4 pa;
            pa[0] = (_Float16)p0; pa[1] = (_Float16)p1;
            pa[2] = (_Float16)p2; pa[3] = (_Float16)p3;
            h4 v0 = *(const h4*)(Vt + l15 * 388 + 16 * mt + 4 * g);
            h4 v1 = *(const h4*)(Vt + v1row * 388 + 16 * mt + 4 * g);
            if (mt & 1) {
                o0b = __builtin_amdgcn_mfma_f32_16x16x16f16(pa, v0, o0b, 0, 0, 0);
                o1b = __builtin_amdgcn_mfma_f32_16x16x16f16(pa, v1, o1b, 0, 0, 0);
            } else {
                o0a = __builtin_amdgcn_mfma_f32_16x16x16f16(pa, v0, o0a, 0, 0, 0);
                o1a = __builtin_amdgcn_mfma_f32_16x16x16f16(pa, v1, o1a, 0, 0, 0);
            }
        }
        f4v o0 = o0a + o0b;
        f4v o1 = o1a + o1b;
        sum += __shfl_xor(sum, 16);
        sum += __shfl_xor(sum, 32);
        // lane (l15,g): sum = row-sum for q=q0+l15

        // normalize -> per-wave LDS tile (wave-private; DS ops are in-order
        // per wave, so only compiler fences are needed, no barrier)
        _Float16* Op = Ob[wid];
        #pragma unroll
        for (int j = 0; j < 4; ++j) {
            float sj = __shfl(sum, 4 * g + j);
            float inv = fast_rcp(sj);
            const int r16 = 4 * g + j;
            Op[r16 * 24 + l15] = (_Float16)(o0[j] * inv);
            if (l15 < 8) Op[r16 * 24 + 16 + l15] = (_Float16)(o1[j] * inv);
        }
        asm volatile("s_waitcnt lgkmcnt(0)" ::: "memory");
        // coalesced 768B burst: 48 lanes x 16B contiguous
        if (lane < 48) {
            h8 ov = *(const h8*)(Op + lane * 8);
            *(h8*)(AOw + (size_t)q0 * 24 + lane * 8) = ov;
        }
        asm volatile("" ::: "memory");  // WAR: pin next-qt Ob writes after this read
    }
}

// ---------------------------------------------------------------------------
// Kernel 4: projection (X @ W^T + b) + window-reverse + roll-back + transpose
// block = half a window (192 tokens), 4 waves x 48 tokens.
// ---------------------------------------------------------------------------
__global__ __launch_bounds__(256) void proj_kernel(
    const _Float16* __restrict__ AOs, const _Float16* __restrict__ Wb,
    const float* __restrict__ bias, float* __restrict__ out)
{
    const int bid = blockIdx.x;
    const int win = bid >> 1, half = bid & 1;
    const int tid = threadIdx.x;
    const int lane = tid & 63, wid = tid >> 6;
    const int l15 = lane & 15, g = lane >> 4;
    const int wi = win >> 6, hi = (win >> 3) & 7, wj = win & 7;

    __shared__ __attribute__((aligned(16))) float tileT[4][192 * 20];
    float* Tw = tileT[wid];

    // per-lane fragment -> (head, sub-chunk) decomposition for m = kk*4+g
    int hdk[6], sbk[6];
    #pragma unroll
    for (int kk = 0; kk < 6; ++kk) {
        int mm = kk * 4 + g;
        hdk[kk] = mm / 3;
        sbk[kk] = mm - 3 * hdk[kk];
    }

    for (int mi = 0; mi < 3; ++mi) {
        __syncthreads();   // WAR: previous epilogue reads done before overwrite
        const int tb = half * 192 + wid * 48 + mi * 16;
        f4v acc[12];
        const f4v zz = {};
        #pragma unroll
        for (int n = 0; n < 12; ++n) acc[n] = zz;
        #pragma unroll
        for (int kk = 0; kk < 6; ++kk) {
            h8 af = *(const h8*)(AOs + (size_t)(hdk[kk] * 256 + win) * 9216
                                     + (size_t)(tb + l15) * 24 + sbk[kk] * 8);
            #pragma unroll
            for (int n = 0; n < 12; ++n) {
                h8 bf = *(const h8*)(Wb + (size_t)(n * 16 + l15) * 192 + kk * 32 + g * 8);
                acc[n] = __builtin_amdgcn_mfma_f32_16x16x32_f16(af, bf, acc[n], 0, 0, 0);
            }
        }
        // bias + transpose through LDS ([c][token16] pad20 -> conflict-free)
        #pragma unroll
        for (int n = 0; n < 12; ++n) {
            float b = bias[n * 16 + l15];
            f4v vv = acc[n];
            vv[0] += b; vv[1] += b; vv[2] += b; vv[3] += b;
            *(f4v*)(Tw + (n * 16 + l15) * 20 + g * 4) = vv;
        }
        __syncthreads();   // make per-wave tile visible across lanes

        // each lane owns one token (i = l15), c = rr*4 + g -> 32B-coalesced stores
        const int i = l15;
        const int nn = tb + i;
        const int twn = nn & 7, thn = (nn >> 3) & 7, tdn = nn >> 6;
        int dd = wi * 6 + tdn + 3; if (dd >= 24) dd -= 24;
        int hh = hi * 8 + thn + 4; if (hh >= 64) hh -= 64;
        int ww = wj * 8 + twn + 4; if (ww >= 64) ww -= 64;
        const size_t sp = (size_t)dd * 4096 + hh * 64 + ww;
        #pragma unroll
        for (int rr = 0; rr < 48; ++rr) {
            const int c = rr * 4 + g;
            out[(size_t)c * 98304 + sp] = Tw[c * 20 + i];
        }
    }
}

// ---------------------------------------------------------------------------
extern "C" void kernel_launch(void* const* d_in, const int* in_sizes, int n_in,
                              void* d_out, int out_size, void* d_ws, size_t ws_size,
                              hipStream_t stream) {
    const float* q_map = (const float*)d_in[0];
    const float* k_map = (const float*)d_in[1];
    const float* v_map = (const float*)d_in[2];
    const float* nqw = (const float*)d_in[3];
    const float* nqb = (const float*)d_in[4];
    const float* nkw = (const float*)d_in[5];
    const float* nkb = (const float*)d_in[6];
    const float* pw = (const float*)d_in[7];
    const float* pb = (const float*)d_in[8];
    float* out = (float*)d_out;

    // workspace layout (f16): Qs, Ks, Vs, AOs each 8*256*384*24 = 18,874,368 elems
    _Float16* ws = (_Float16*)d_ws;
    const size_t BUF = (size_t)8 * 256 * 384 * 24;
    _Float16* Qs = ws;
    _Float16* Ks = ws + BUF;
    _Float16* Vs = ws + 2 * BUF;
    _Float16* AOs = ws + 3 * BUF;
    _Float16* Wb = ws + 4 * BUF;   // + 73728 B, total ~151 MB

    ln_stage_kernel<<<dim3(1536, 3), 256, 0, stream>>>(q_map, k_map, v_map,
                                                       nqw, nqb, nkw, nkb, Qs, Ks, Vs);
    wconv_kernel<<<144, 256, 0, stream>>>(pw, Wb);
    attn_kernel<<<dim3(256, 8), 256, 0, stream>>>(Qs, Ks, Vs, AOs);
    proj_kernel<<<512, 256, 0, stream>>>(AOs, Wb, pb, out);
}

// Round 11
// 338.594 us; speedup vs baseline: 1.2210x; 1.0820x over previous
//
#include <hip/hip_runtime.h>

typedef float f4v __attribute__((ext_vector_type(4)));
typedef _Float16 h8 __attribute__((ext_vector_type(8)));
typedef _Float16 h4 __attribute__((ext_vector_type(4)));

// Problem constants
// C=192, NH=8, DH=24, window 6x8x8 -> N=384 tokens, D/H/W = 24/64/64 -> 256 windows
// shift (3,4,4). Spatial stride per channel = 24*64*64 = 98304.
// Staging layout (f16): [head][win][n][24]  -> slab (head,win) = 384*24 = 9216 elems.

__device__ __forceinline__ float fast_exp2(float x) {
#if __has_builtin(__builtin_amdgcn_exp2f)
    return __builtin_amdgcn_exp2f(x);
#else
    return exp2f(x);
#endif
}
__device__ __forceinline__ float fast_rcp(float x) {
#if __has_builtin(__builtin_amdgcn_rcpf)
    return __builtin_amdgcn_rcpf(x);
#else
    return 1.0f / x;
#endif
}

// ---------------------------------------------------------------------------
// Kernel 1: transpose + roll + window-partition + LayerNorm -> f16 staging
// ---------------------------------------------------------------------------
__global__ __launch_bounds__(256) void ln_stage_kernel(
    const float* __restrict__ q, const float* __restrict__ k, const float* __restrict__ v,
    const float* __restrict__ nqw, const float* __restrict__ nqb,
    const float* __restrict__ nkw, const float* __restrict__ nkb,
    _Float16* __restrict__ Qs, _Float16* __restrict__ Ks, _Float16* __restrict__ Vs)
{
    const int tid = threadIdx.x;
    const int bid = blockIdx.x;      // d*64 + h
    const int tensor = blockIdx.y;   // 0=q, 1=k, 2=v
    const int d = bid >> 6;
    const int h = bid & 63;

    const float* src = (tensor == 0) ? q : (tensor == 1) ? k : v;
    const float* gam = (tensor == 0) ? nqw : nkw;
    const float* bet = (tensor == 0) ? nqb : nkb;
    _Float16* dst = (tensor == 0) ? Qs : (tensor == 1) ? Ks : Vs;
    // fold softmax scale (1/sqrt(24)) and log2(e) into Q so scores are in exp2 domain
    const float scale = (tensor == 0) ? (0.20412414523193154f * 1.44269504088896340f) : 1.0f;

    __shared__ __attribute__((aligned(16))) float tile[192][64];
    __shared__ float psum[4][64];
    __shared__ float psq[4][64];
    __shared__ float smean[64];
    __shared__ float srstd[64];
    __shared__ float sgam[192];
    __shared__ float sbet[192];

    if (tid < 192) { sgam[tid] = gam[tid]; sbet[tid] = bet[tid]; }

    // coalesced load of 192 channels x 64 w (256B per row)
    {
        const float* base = src + (size_t)d * 4096 + (size_t)h * 64;
        const int c0 = tid >> 4;
        const int col = (tid & 15) << 2;
        #pragma unroll
        for (int r = 0; r < 12; ++r) {
            int c = r * 16 + c0;
            f4v x = *(const f4v*)(base + (size_t)c * 98304 + col);
            *(f4v*)&tile[c][col] = x;
        }
    }
    __syncthreads();

    // per-token (per-w-column) mean / var
    {
        const int wcol = tid & 63;
        const int p = tid >> 6;
        float s = 0.f, ss = 0.f;
        #pragma unroll
        for (int i = 0; i < 48; ++i) {
            float x = tile[p * 48 + i][wcol];
            s += x; ss += x * x;
        }
        psum[p][wcol] = s; psq[p][wcol] = ss;
    }
    __syncthreads();
    if (tid < 64) {
        float S  = psum[0][tid] + psum[1][tid] + psum[2][tid] + psum[3][tid];
        float SS = psq[0][tid] + psq[1][tid] + psq[2][tid] + psq[3][tid];
        float mean = S * (1.0f / 192.0f);
        float var = SS * (1.0f / 192.0f) - mean * mean;
        smean[tid] = mean;
        srstd[tid] = rsqrtf(var + 1e-5f);
    }
    __syncthreads();

    // normalize + write f16 staging, head-major: [head][win][n][24]
    {
        const int wpos = tid >> 2;   // 0..63 source w
        const int p = tid & 3;       // channel quarter = heads 2p, 2p+1
        const float mean = smean[wpos];
        const float rstd = srstd[wpos];
        int d_r = d + 21; if (d_r >= 24) d_r -= 24;
        int h_r = h + 60; if (h_r >= 64) h_r -= 64;
        int w_r = wpos + 60; if (w_r >= 64) w_r -= 64;
        const int wi = d_r / 6, td = d_r - wi * 6;
        const int hi = h_r >> 3, th = h_r & 7;
        const int wj = w_r >> 3, tw = w_r & 7;
        const int win = (wi * 8 + hi) * 8 + wj;
        const int n = (td * 8 + th) * 8 + tw;
        #pragma unroll
        for (int hh2 = 0; hh2 < 2; ++hh2) {
            const int head = p * 2 + hh2;
            _Float16* outp = dst + (size_t)(head * 256 + win) * 9216 + n * 24;
            #pragma unroll
            for (int cc = 0; cc < 3; ++cc) {
                const int c = head * 24 + cc * 8;
                h8 hv;
                #pragma unroll
                for (int j = 0; j < 8; ++j) {
                    float x = (tile[c + j][wpos] - mean) * rstd * sgam[c + j] + sbet[c + j];
                    hv[j] = (_Float16)(x * scale);
                }
                *(h8*)(outp + cc * 8) = hv;
            }
        }
    }
}

// ---------------------------------------------------------------------------
// Kernel 2: proj_w f32 -> f16
// ---------------------------------------------------------------------------
__global__ __launch_bounds__(256) void wconv_kernel(const float* __restrict__ w,
                                                    _Float16* __restrict__ wb)
{
    int i = blockIdx.x * 256 + threadIdx.x;
    if (i < 192 * 192) wb[i] = (_Float16)w[i];
}

// ---------------------------------------------------------------------------
// Kernel 3: windowed attention, one block per (window, head). 8 WAVES (512t):
// same K/V LDS staging shared by twice the waves -> 24 waves/CU (vs 12)
// at unchanged ~43.6KB LDS (3 blocks/CU). Each wave owns 48 q-rows (3 qt).
// NO-MAX softmax: p = exp2(s - 6), -6 folded into QK MFMA C-init.
// QK -> exp -> PV fused in ONE mt loop; o accumulators split a/b.
// (x,4)-style aggressive bounds forbidden: 64-VGPR allocation -> spills
// (confirmed r5, r9). (512,3) keeps allocator at natural ~80 VGPR.
// ---------------------------------------------------------------------------
__global__ __launch_bounds__(512, 3) void attn_kernel(
    const _Float16* __restrict__ Qs, const _Float16* __restrict__ Ks,
    const _Float16* __restrict__ Vs, _Float16* __restrict__ AOs)
{
    const int win = blockIdx.x;
    const int head = blockIdx.y;
    const int tid = threadIdx.x;
    const int lane = tid & 63;
    const int wid = tid >> 6;        // 0..7
    const int l15 = lane & 15;
    const int g = lane >> 4;

    __shared__ __attribute__((aligned(16))) _Float16 Kh[384 * 24 + 8]; // [token][24] + zero tail
    __shared__ __attribute__((aligned(16))) _Float16 Vt[24 * 388];     // [dh][token pad388]
    __shared__ __attribute__((aligned(16))) _Float16 Ob[8][16 * 24];   // per-wave output tile
    __shared__ __attribute__((aligned(4)))  unsigned char rid[384];

    const int wi = win >> 6, hi = (win >> 3) & 7, wj = win & 7;
    const bool mixed = (wi == 3) || (hi == 7) || (wj == 7);

    const size_t slab = (size_t)(head * 256 + win) * 9216;
    const _Float16* Kw = Ks + slab;
    const _Float16* Vw = Vs + slab;
    const _Float16* Qw = Qs + slab;
    _Float16* AOw = AOs + slab;

    // ---- hoist this wave's 3 Q fragments (issued before staging; overlap) ----
    // g==3 chunk MUST be exactly zero (matching K chunk is next-row data).
    h8 qreg[3];
    #pragma unroll
    for (int qt = 0; qt < 3; ++qt) {
        h8 z = {};
        qreg[qt] = z;
        if (g < 3)
            qreg[qt] = *(const h8*)(Qw + (size_t)(wid * 48 + qt * 16 + l15) * 24 + g * 8);
    }

    // ---- stage K (flat copy) and V^T (transpose), region ids ----
    {
        const h8* K8 = (const h8*)Kw;
        const h8* V8 = (const h8*)Vw;
        #pragma unroll
        for (int it = 0; it < 5; ++it) {
            int idx = it * 512 + tid;        // 0..2303 ; 0..1151 = K, 1152.. = V
            if (idx < 1152) {
                *(h8*)(Kh + idx * 8) = K8[idx];
            } else if (idx < 2304) {
                int i = idx - 1152;          // flat h8 index in V slab
                int n = i / 3;               // token
                int ch = i - n * 3;          // 8-dh chunk
                h8 vv = V8[i];
                #pragma unroll
                for (int j = 0; j < 8; ++j) Vt[(ch * 8 + j) * 388 + n] = vv[j];
            }
        }
        if (tid == 0) {  // zero the 8-elem overhang read by (mt=23,l15=15,g=3)
            const h8 z8 = {};
            *(h8*)(Kh + 384 * 24) = z8;
        }
        if (tid < 384) {
            const int n = tid;
            int twn = n & 7, thn = (n >> 3) & 7, tdn = n >> 6;
            int rd = (wi == 3) ? (tdn < 3 ? 1 : 2) : 0;
            int rh = (hi == 7) ? (thn < 4 ? 1 : 2) : 0;
            int rw = (wj == 7) ? (twn < 4 ? 1 : 2) : 0;
            rid[n] = (unsigned char)(rd * 9 + rh * 3 + rw);
        }
    }
    __syncthreads();

    const int v1row = 16 + (l15 & 7);   // lanes 8-15 duplicate rows 16-23 (discarded cols)

    for (int qt = 0; qt < 3; ++qt) {
        const int q0 = wid * 48 + qt * 16;
        const h8 qf = qreg[qt];
        const unsigned int rq = rid[q0 + l15];

        float sum = 0.f;
        f4v o0a = {}, o0b = {}, o1a = {}, o1b = {};
        #pragma unroll
        for (int mt = 0; mt < 24; ++mt) {
            h8 kf = *(const h8*)(Kh + (16 * mt + l15) * 24 + g * 8);
            const f4v cinit = {-6.f, -6.f, -6.f, -6.f};
            f4v s4 = __builtin_amdgcn_mfma_f32_16x16x32_f16(kf, qf, cinit, 0, 0, 0);
            // lane (l15,g): s4[j] = S[q=q0+l15][k=16mt+4g+j] - 6
            if (mixed) {
                unsigned int r4 = *(const unsigned int*)(rid + 16 * mt + 4 * g);
                #pragma unroll
                for (int j = 0; j < 4; ++j) {
                    if (((r4 >> (8 * j)) & 255u) != rq) s4[j] = -1e30f;
                }
            }
            float p0 = fast_exp2(s4[0]);
            float p1 = fast_exp2(s4[1]);
            float p2 = fast_exp2(s4[2]);
            float p3 = fast_exp2(s4[3]);
            sum += (p0 + p1) + (p2 + p3);
            h4 pa;
            pa[0] = (_Float16)p0; pa[1] = (_Float16)p1;
            pa[2] = (_Float16)p2; pa[3] = (_Float16)p3;
            h4 v0 = *(const h4*)(Vt + l15 * 388 + 16 * mt + 4 * g);
            h4 v1 = *(const h4*)(Vt + v1row * 388 + 16 * mt + 4 * g);
            if (mt & 1) {
                o0b = __builtin_amdgcn_mfma_f32_16x16x16f16(pa, v0, o0b, 0, 0, 0);
                o1b = __builtin_amdgcn_mfma_f32_16x16x16f16(pa, v1, o1b, 0, 0, 0);
            } else {
                o0a = __builtin_amdgcn_mfma_f32_16x16x16f16(pa, v0, o0a, 0, 0, 0);
                o1a = __builtin_amdgcn_mfma_f32_16x16x16f16(pa, v1, o1a, 0, 0, 0);
            }
        }
        f4v o0 = o0a + o0b;
        f4v o1 = o1a + o1b;
        sum += __shfl_xor(sum, 16);
        sum += __shfl_xor(sum, 32);
        // lane (l15,g): sum = row-sum for q=q0+l15

        // normalize -> per-wave LDS tile (wave-private; DS ops are in-order
        // per wave, so only compiler fences are needed, no barrier)
        _Float16* Op = Ob[wid];
        #pragma unroll
        for (int j = 0; j < 4; ++j) {
            float sj = __shfl(sum, 4 * g + j);
            float inv = fast_rcp(sj);
            const int r16 = 4 * g + j;
            Op[r16 * 24 + l15] = (_Float16)(o0[j] * inv);
            if (l15 < 8) Op[r16 * 24 + 16 + l15] = (_Float16)(o1[j] * inv);
        }
        asm volatile("s_waitcnt lgkmcnt(0)" ::: "memory");
        // coalesced 768B burst: 48 lanes x 16B contiguous
        if (lane < 48) {
            h8 ov = *(const h8*)(Op + lane * 8);
            *(h8*)(AOw + (size_t)q0 * 24 + lane * 8) = ov;
        }
        asm volatile("" ::: "memory");  // WAR: pin next-qt Ob writes after this read
    }
}

// ---------------------------------------------------------------------------
// Kernel 4: projection (X @ W^T + b) + window-reverse + roll-back + transpose
// block = half a window (192 tokens), 4 waves x 48 tokens.
// ---------------------------------------------------------------------------
__global__ __launch_bounds__(256) void proj_kernel(
    const _Float16* __restrict__ AOs, const _Float16* __restrict__ Wb,
    const float* __restrict__ bias, float* __restrict__ out)
{
    const int bid = blockIdx.x;
    const int win = bid >> 1, half = bid & 1;
    const int tid = threadIdx.x;
    const int lane = tid & 63, wid = tid >> 6;
    const int l15 = lane & 15, g = lane >> 4;
    const int wi = win >> 6, hi = (win >> 3) & 7, wj = win & 7;

    __shared__ __attribute__((aligned(16))) float tileT[4][192 * 20];
    float* Tw = tileT[wid];

    // per-lane fragment -> (head, sub-chunk) decomposition for m = kk*4+g
    int hdk[6], sbk[6];
    #pragma unroll
    for (int kk = 0; kk < 6; ++kk) {
        int mm = kk * 4 + g;
        hdk[kk] = mm / 3;
        sbk[kk] = mm - 3 * hdk[kk];
    }

    for (int mi = 0; mi < 3; ++mi) {
        __syncthreads();   // WAR: previous epilogue reads done before overwrite
        const int tb = half * 192 + wid * 48 + mi * 16;
        f4v acc[12];
        const f4v zz = {};
        #pragma unroll
        for (int n = 0; n < 12; ++n) acc[n] = zz;
        #pragma unroll
        for (int kk = 0; kk < 6; ++kk) {
            h8 af = *(const h8*)(AOs + (size_t)(hdk[kk] * 256 + win) * 9216
                                     + (size_t)(tb + l15) * 24 + sbk[kk] * 8);
            #pragma unroll
            for (int n = 0; n < 12; ++n) {
                h8 bf = *(const h8*)(Wb + (size_t)(n * 16 + l15) * 192 + kk * 32 + g * 8);
                acc[n] = __builtin_amdgcn_mfma_f32_16x16x32_f16(af, bf, acc[n], 0, 0, 0);
            }
        }
        // bias + transpose through LDS ([c][token16] pad20 -> conflict-free)
        #pragma unroll
        for (int n = 0; n < 12; ++n) {
            float b = bias[n * 16 + l15];
            f4v vv = acc[n];
            vv[0] += b; vv[1] += b; vv[2] += b; vv[3] += b;
            *(f4v*)(Tw + (n * 16 + l15) * 20 + g * 4) = vv;
        }
        __syncthreads();   // make per-wave tile visible across lanes

        // each lane owns one token (i = l15), c = rr*4 + g -> 32B-coalesced stores
        const int i = l15;
        const int nn = tb + i;
        const int twn = nn & 7, thn = (nn >> 3) & 7, tdn = nn >> 6;
        int dd = wi * 6 + tdn + 3; if (dd >= 24) dd -= 24;
        int hh = hi * 8 + thn + 4; if (hh >= 64) hh -= 64;
        int ww = wj * 8 + twn + 4; if (ww >= 64) ww -= 64;
        const size_t sp = (size_t)dd * 4096 + hh * 64 + ww;
        #pragma unroll
        for (int rr = 0; rr < 48; ++rr) {
            const int c = rr * 4 + g;
            out[(size_t)c * 98304 + sp] = Tw[c * 20 + i];
        }
    }
}

// ---------------------------------------------------------------------------
extern "C" void kernel_launch(void* const* d_in, const int* in_sizes, int n_in,
                              void* d_out, int out_size, void* d_ws, size_t ws_size,
                              hipStream_t stream) {
    const float* q_map = (const float*)d_in[0];
    const float* k_map = (const float*)d_in[1];
    const float* v_map = (const float*)d_in[2];
    const float* nqw = (const float*)d_in[3];
    const float* nqb = (const float*)d_in[4];
    const float* nkw = (const float*)d_in[5];
    const float* nkb = (const float*)d_in[6];
    const float* pw = (const float*)d_in[7];
    const float* pb = (const float*)d_in[8];
    float* out = (float*)d_out;

    // workspace layout (f16): Qs, Ks, Vs, AOs each 8*256*384*24 = 18,874,368 elems
    _Float16* ws = (_Float16*)d_ws;
    const size_t BUF = (size_t)8 * 256 * 384 * 24;
    _Float16* Qs = ws;
    _Float16* Ks = ws + BUF;
    _Float16* Vs = ws + 2 * BUF;
    _Float16* AOs = ws + 3 * BUF;
    _Float16* Wb = ws + 4 * BUF;   // + 73728 B, total ~151 MB

    ln_stage_kernel<<<dim3(1536, 3), 256, 0, stream>>>(q_map, k_map, v_map,
                                                       nqw, nqb, nkw, nkb, Qs, Ks, Vs);
    wconv_kernel<<<144, 256, 0, stream>>>(pw, Wb);
    attn_kernel<<<dim3(256, 8), 512, 0, stream>>>(Qs, Ks, Vs, AOs);
    proj_kernel<<<512, 256, 0, stream>>>(AOs, Wb, pb, out);
}

// Round 12
// 330.232 us; speedup vs baseline: 1.2520x; 1.0253x over previous
//
#include <hip/hip_runtime.h>

typedef float f4v __attribute__((ext_vector_type(4)));
typedef _Float16 h8 __attribute__((ext_vector_type(8)));
typedef _Float16 h4 __attribute__((ext_vector_type(4)));

// Problem constants
// C=192, NH=8, DH=24, window 6x8x8 -> N=384 tokens, D/H/W = 24/64/64 -> 256 windows
// shift (3,4,4). Spatial stride per channel = 24*64*64 = 98304.
// Staging layout (f16): [head][win][n][24]  -> slab (head,win) = 384*24 = 9216 elems.

__device__ __forceinline__ float fast_exp2(float x) {
#if __has_builtin(__builtin_amdgcn_exp2f)
    return __builtin_amdgcn_exp2f(x);
#else
    return exp2f(x);
#endif
}
__device__ __forceinline__ float fast_rcp(float x) {
#if __has_builtin(__builtin_amdgcn_rcpf)
    return __builtin_amdgcn_rcpf(x);
#else
    return 1.0f / x;
#endif
}

// ---------------------------------------------------------------------------
// Kernel 1: transpose + roll + window-partition + LayerNorm -> f16 staging
// (at HBM roofline: 339MB moved in ~60us ~ 90% of achievable — do not touch)
// ---------------------------------------------------------------------------
__global__ __launch_bounds__(256) void ln_stage_kernel(
    const float* __restrict__ q, const float* __restrict__ k, const float* __restrict__ v,
    const float* __restrict__ nqw, const float* __restrict__ nqb,
    const float* __restrict__ nkw, const float* __restrict__ nkb,
    _Float16* __restrict__ Qs, _Float16* __restrict__ Ks, _Float16* __restrict__ Vs)
{
    const int tid = threadIdx.x;
    const int bid = blockIdx.x;      // d*64 + h
    const int tensor = blockIdx.y;   // 0=q, 1=k, 2=v
    const int d = bid >> 6;
    const int h = bid & 63;

    const float* src = (tensor == 0) ? q : (tensor == 1) ? k : v;
    const float* gam = (tensor == 0) ? nqw : nkw;
    const float* bet = (tensor == 0) ? nqb : nkb;
    _Float16* dst = (tensor == 0) ? Qs : (tensor == 1) ? Ks : Vs;
    // fold softmax scale (1/sqrt(24)) and log2(e) into Q so scores are in exp2 domain
    const float scale = (tensor == 0) ? (0.20412414523193154f * 1.44269504088896340f) : 1.0f;

    __shared__ __attribute__((aligned(16))) float tile[192][64];
    __shared__ float psum[4][64];
    __shared__ float psq[4][64];
    __shared__ float smean[64];
    __shared__ float srstd[64];
    __shared__ float sgam[192];
    __shared__ float sbet[192];

    if (tid < 192) { sgam[tid] = gam[tid]; sbet[tid] = bet[tid]; }

    // coalesced load of 192 channels x 64 w (256B per row)
    {
        const float* base = src + (size_t)d * 4096 + (size_t)h * 64;
        const int c0 = tid >> 4;
        const int col = (tid & 15) << 2;
        #pragma unroll
        for (int r = 0; r < 12; ++r) {
            int c = r * 16 + c0;
            f4v x = *(const f4v*)(base + (size_t)c * 98304 + col);
            *(f4v*)&tile[c][col] = x;
        }
    }
    __syncthreads();

    // per-token (per-w-column) mean / var
    {
        const int wcol = tid & 63;
        const int p = tid >> 6;
        float s = 0.f, ss = 0.f;
        #pragma unroll
        for (int i = 0; i < 48; ++i) {
            float x = tile[p * 48 + i][wcol];
            s += x; ss += x * x;
        }
        psum[p][wcol] = s; psq[p][wcol] = ss;
    }
    __syncthreads();
    if (tid < 64) {
        float S  = psum[0][tid] + psum[1][tid] + psum[2][tid] + psum[3][tid];
        float SS = psq[0][tid] + psq[1][tid] + psq[2][tid] + psq[3][tid];
        float mean = S * (1.0f / 192.0f);
        float var = SS * (1.0f / 192.0f) - mean * mean;
        smean[tid] = mean;
        srstd[tid] = rsqrtf(var + 1e-5f);
    }
    __syncthreads();

    // normalize + write f16 staging, head-major: [head][win][n][24]
    {
        const int wpos = tid >> 2;   // 0..63 source w
        const int p = tid & 3;       // channel quarter = heads 2p, 2p+1
        const float mean = smean[wpos];
        const float rstd = srstd[wpos];
        int d_r = d + 21; if (d_r >= 24) d_r -= 24;
        int h_r = h + 60; if (h_r >= 64) h_r -= 64;
        int w_r = wpos + 60; if (w_r >= 64) w_r -= 64;
        const int wi = d_r / 6, td = d_r - wi * 6;
        const int hi = h_r >> 3, th = h_r & 7;
        const int wj = w_r >> 3, tw = w_r & 7;
        const int win = (wi * 8 + hi) * 8 + wj;
        const int n = (td * 8 + th) * 8 + tw;
        #pragma unroll
        for (int hh2 = 0; hh2 < 2; ++hh2) {
            const int head = p * 2 + hh2;
            _Float16* outp = dst + (size_t)(head * 256 + win) * 9216 + n * 24;
            #pragma unroll
            for (int cc = 0; cc < 3; ++cc) {
                const int c = head * 24 + cc * 8;
                h8 hv;
                #pragma unroll
                for (int j = 0; j < 8; ++j) {
                    float x = (tile[c + j][wpos] - mean) * rstd * sgam[c + j] + sbet[c + j];
                    hv[j] = (_Float16)(x * scale);
                }
                *(h8*)(outp + cc * 8) = hv;
            }
        }
    }
}

// ---------------------------------------------------------------------------
// Kernel 2: proj_w f32 -> f16
// ---------------------------------------------------------------------------
__global__ __launch_bounds__(256) void wconv_kernel(const float* __restrict__ w,
                                                    _Float16* __restrict__ wb)
{
    int i = blockIdx.x * 256 + threadIdx.x;
    if (i < 192 * 192) wb[i] = (_Float16)w[i];
}

// ---------------------------------------------------------------------------
// Kernel 3: windowed attention, one block per (window, head). 8 WAVES (512t).
// NO-MAX softmax: p = exp2(s - 6), -6 folded into QK MFMA C-init.
// QK -> exp -> PV fused in ONE mt loop; o accumulators split a/b.
// VGPR sits exactly at the 6-wave/SIMD boundary (84) — do NOT add registers;
// (x,4)-style bounds forbidden: 64-VGPR allocation -> spills (r5, r9).
// ---------------------------------------------------------------------------
__global__ __launch_bounds__(512, 3) void attn_kernel(
    const _Float16* __restrict__ Qs, const _Float16* __restrict__ Ks,
    const _Float16* __restrict__ Vs, _Float16* __restrict__ AOs)
{
    const int win = blockIdx.x;
    const int head = blockIdx.y;
    const int tid = threadIdx.x;
    const int lane = tid & 63;
    const int wid = tid >> 6;        // 0..7
    const int l15 = lane & 15;
    const int g = lane >> 4;

    __shared__ __attribute__((aligned(16))) _Float16 Kh[384 * 24 + 8]; // [token][24] + zero tail
    __shared__ __attribute__((aligned(16))) _Float16 Vt[24 * 388];     // [dh][token pad388]
    __shared__ __attribute__((aligned(16))) _Float16 Ob[8][16 * 24];   // per-wave output tile
    __shared__ __attribute__((aligned(4)))  unsigned char rid[384];

    const int wi = win >> 6, hi = (win >> 3) & 7, wj = win & 7;
    const bool mixed = (wi == 3) || (hi == 7) || (wj == 7);

    const size_t slab = (size_t)(head * 256 + win) * 9216;
    const _Float16* Kw = Ks + slab;
    const _Float16* Vw = Vs + slab;
    const _Float16* Qw = Qs + slab;
    _Float16* AOw = AOs + slab;

    // ---- hoist this wave's 3 Q fragments (issued before staging; overlap) ----
    // g==3 chunk MUST be exactly zero (matching K chunk is next-row data).
    h8 qreg[3];
    #pragma unroll
    for (int qt = 0; qt < 3; ++qt) {
        h8 z = {};
        qreg[qt] = z;
        if (g < 3)
            qreg[qt] = *(const h8*)(Qw + (size_t)(wid * 48 + qt * 16 + l15) * 24 + g * 8);
    }

    // ---- stage K (flat copy) and V^T (transpose), region ids ----
    {
        const h8* K8 = (const h8*)Kw;
        const h8* V8 = (const h8*)Vw;
        #pragma unroll
        for (int it = 0; it < 5; ++it) {
            int idx = it * 512 + tid;        // 0..2303 ; 0..1151 = K, 1152.. = V
            if (idx < 1152) {
                *(h8*)(Kh + idx * 8) = K8[idx];
            } else if (idx < 2304) {
                int i = idx - 1152;          // flat h8 index in V slab
                int n = i / 3;               // token
                int ch = i - n * 3;          // 8-dh chunk
                h8 vv = V8[i];
                #pragma unroll
                for (int j = 0; j < 8; ++j) Vt[(ch * 8 + j) * 388 + n] = vv[j];
            }
        }
        if (tid == 0) {  // zero the 8-elem overhang read by (mt=23,l15=15,g=3)
            const h8 z8 = {};
            *(h8*)(Kh + 384 * 24) = z8;
        }
        if (tid < 384) {
            const int n = tid;
            int twn = n & 7, thn = (n >> 3) & 7, tdn = n >> 6;
            int rd = (wi == 3) ? (tdn < 3 ? 1 : 2) : 0;
            int rh = (hi == 7) ? (thn < 4 ? 1 : 2) : 0;
            int rw = (wj == 7) ? (twn < 4 ? 1 : 2) : 0;
            rid[n] = (unsigned char)(rd * 9 + rh * 3 + rw);
        }
    }
    __syncthreads();

    const int v1row = 16 + (l15 & 7);   // lanes 8-15 duplicate rows 16-23 (discarded cols)

    for (int qt = 0; qt < 3; ++qt) {
        const int q0 = wid * 48 + qt * 16;
        const h8 qf = qreg[qt];
        const unsigned int rq = rid[q0 + l15];

        float sum = 0.f;
        f4v o0a = {}, o0b = {}, o1a = {}, o1b = {};
        #pragma unroll
        for (int mt = 0; mt < 24; ++mt) {
            h8 kf = *(const h8*)(Kh + (16 * mt + l15) * 24 + g * 8);
            const f4v cinit = {-6.f, -6.f, -6.f, -6.f};
            f4v s4 = __builtin_amdgcn_mfma_f32_16x16x32_f16(kf, qf, cinit, 0, 0, 0);
            // lane (l15,g): s4[j] = S[q=q0+l15][k=16mt+4g+j] - 6
            if (mixed) {
                unsigned int r4 = *(const unsigned int*)(rid + 16 * mt + 4 * g);
                #pragma unroll
                for (int j = 0; j < 4; ++j) {
                    if (((r4 >> (8 * j)) & 255u) != rq) s4[j] = -1e30f;
                }
            }
            float p0 = fast_exp2(s4[0]);
            float p1 = fast_exp2(s4[1]);
            float p2 = fast_exp2(s4[2]);
            float p3 = fast_exp2(s4[3]);
            sum += (p0 + p1) + (p2 + p3);
            h4 pa;
            pa[0] = (_Float16)p0; pa[1] = (_Float16)p1;
            pa[2] = (_Float16)p2; pa[3] = (_Float16)p3;
            h4 v0 = *(const h4*)(Vt + l15 * 388 + 16 * mt + 4 * g);
            h4 v1 = *(const h4*)(Vt + v1row * 388 + 16 * mt + 4 * g);
            if (mt & 1) {
                o0b = __builtin_amdgcn_mfma_f32_16x16x16f16(pa, v0, o0b, 0, 0, 0);
                o1b = __builtin_amdgcn_mfma_f32_16x16x16f16(pa, v1, o1b, 0, 0, 0);
            } else {
                o0a = __builtin_amdgcn_mfma_f32_16x16x16f16(pa, v0, o0a, 0, 0, 0);
                o1a = __builtin_amdgcn_mfma_f32_16x16x16f16(pa, v1, o1a, 0, 0, 0);
            }
        }
        f4v o0 = o0a + o0b;
        f4v o1 = o1a + o1b;
        sum += __shfl_xor(sum, 16);
        sum += __shfl_xor(sum, 32);
        // lane (l15,g): sum = row-sum for q=q0+l15

        // normalize -> per-wave LDS tile (wave-private; DS ops are in-order
        // per wave, so only compiler fences are needed, no barrier)
        _Float16* Op = Ob[wid];
        #pragma unroll
        for (int j = 0; j < 4; ++j) {
            float sj = __shfl(sum, 4 * g + j);
            float inv = fast_rcp(sj);
            const int r16 = 4 * g + j;
            Op[r16 * 24 + l15] = (_Float16)(o0[j] * inv);
            if (l15 < 8) Op[r16 * 24 + 16 + l15] = (_Float16)(o1[j] * inv);
        }
        asm volatile("s_waitcnt lgkmcnt(0)" ::: "memory");
        // coalesced 768B burst: 48 lanes x 16B contiguous
        if (lane < 48) {
            h8 ov = *(const h8*)(Op + lane * 8);
            *(h8*)(AOw + (size_t)q0 * 24 + lane * 8) = ov;
        }
        asm volatile("" ::: "memory");  // WAR: pin next-qt Ob writes after this read
    }
}

// ---------------------------------------------------------------------------
// Kernel 4: projection (X @ W^T + b) + window-reverse + roll-back + transpose
// RESTRUCTURED (r12): grid 1536 = win x half x mi (64 tokens/block, 4 waves x
// 16 tokens) — no serial mi loop, no barriers (tileT is wave-private; same-wave
// DS round trip uses the attn-proven lgkmcnt fence). af[6] preloaded +
// n-outer/kk-inner MFMA loop cuts live VGPR from 256 (full-unroll bf pileup)
// to ~110 -> 4 waves/SIMD. tileT pad 17 (odd -> conflict-free writes):
// 52.2KB -> 3 blocks/CU = 12 waves/CU (vs 8).
// ---------------------------------------------------------------------------
__global__ __launch_bounds__(256) void proj_kernel(
    const _Float16* __restrict__ AOs, const _Float16* __restrict__ Wb,
    const float* __restrict__ bias, float* __restrict__ out)
{
    const int bid = blockIdx.x;             // 0..1535
    const int win = bid / 6;
    const int r6 = bid - win * 6;
    const int half = r6 / 3;
    const int mi = r6 - half * 3;
    const int tid = threadIdx.x;
    const int lane = tid & 63, wid = tid >> 6;
    const int l15 = lane & 15, g = lane >> 4;
    const int wi = win >> 6, hi = (win >> 3) & 7, wj = win & 7;

    __shared__ __attribute__((aligned(16))) float tileT[4][192 * 17];
    float* Tw = tileT[wid];

    const int tb = half * 192 + mi * 64 + wid * 16;

    // per-lane fragment -> (head, sub-chunk) decomposition for m = kk*4+g
    // (8-channel chunk m lies entirely in head m/3 since 24 = 3*8)
    int hdk[6], sbk[6];
    #pragma unroll
    for (int kk = 0; kk < 6; ++kk) {
        int mm = kk * 4 + g;
        hdk[kk] = mm / 3;
        sbk[kk] = mm - 3 * hdk[kk];
    }

    // preload this wave's 6 A-fragments (16 tokens x 32 channels each)
    h8 af[6];
    #pragma unroll
    for (int kk = 0; kk < 6; ++kk)
        af[kk] = *(const h8*)(AOs + (size_t)(hdk[kk] * 256 + win) * 9216
                                  + (size_t)(tb + l15) * 24 + sbk[kk] * 8);

    // GEMM: n-outer, kk-inner (bounds live bf fragments; acc[n] hot)
    f4v acc[12];
    #pragma unroll
    for (int n = 0; n < 12; ++n) {
        f4v a = {};
        #pragma unroll
        for (int kk = 0; kk < 6; ++kk) {
            h8 bf = *(const h8*)(Wb + (size_t)(n * 16 + l15) * 192 + kk * 32 + g * 8);
            a = __builtin_amdgcn_mfma_f32_16x16x32_f16(af[kk], bf, a, 0, 0, 0);
        }
        acc[n] = a;
    }

    // bias + transpose through wave-private LDS ([c][token16] pad17)
    #pragma unroll
    for (int n = 0; n < 12; ++n) {
        float b = bias[n * 16 + l15];
        f4v vv = acc[n];
        vv[0] += b; vv[1] += b; vv[2] += b; vv[3] += b;
        *(f4v*)(Tw + (n * 16 + l15) * 17 + g * 4) = vv;
    }
    asm volatile("s_waitcnt lgkmcnt(0)" ::: "memory");

    // each lane owns one token (i = l15), c = rr*4 + g -> 32B-coalesced stores
    const int i = l15;
    const int nn = tb + i;
    const int twn = nn & 7, thn = (nn >> 3) & 7, tdn = nn >> 6;
    int dd = wi * 6 + tdn + 3; if (dd >= 24) dd -= 24;
    int hh = hi * 8 + thn + 4; if (hh >= 64) hh -= 64;
    int ww = wj * 8 + twn + 4; if (ww >= 64) ww -= 64;
    const size_t sp = (size_t)dd * 4096 + hh * 64 + ww;
    #pragma unroll
    for (int rr = 0; rr < 48; ++rr) {
        const int c = rr * 4 + g;
        out[(size_t)c * 98304 + sp] = Tw[c * 17 + i];
    }
}

// ---------------------------------------------------------------------------
extern "C" void kernel_launch(void* const* d_in, const int* in_sizes, int n_in,
                              void* d_out, int out_size, void* d_ws, size_t ws_size,
                              hipStream_t stream) {
    const float* q_map = (const float*)d_in[0];
    const float* k_map = (const float*)d_in[1];
    const float* v_map = (const float*)d_in[2];
    const float* nqw = (const float*)d_in[3];
    const float* nqb = (const float*)d_in[4];
    const float* nkw = (const float*)d_in[5];
    const float* nkb = (const float*)d_in[6];
    const float* pw = (const float*)d_in[7];
    const float* pb = (const float*)d_in[8];
    float* out = (float*)d_out;

    // workspace layout (f16): Qs, Ks, Vs, AOs each 8*256*384*24 = 18,874,368 elems
    _Float16* ws = (_Float16*)d_ws;
    const size_t BUF = (size_t)8 * 256 * 384 * 24;
    _Float16* Qs = ws;
    _Float16* Ks = ws + BUF;
    _Float16* Vs = ws + 2 * BUF;
    _Float16* AOs = ws + 3 * BUF;
    _Float16* Wb = ws + 4 * BUF;   // + 73728 B, total ~151 MB

    ln_stage_kernel<<<dim3(1536, 3), 256, 0, stream>>>(q_map, k_map, v_map,
                                                       nqw, nqb, nkw, nkb, Qs, Ks, Vs);
    wconv_kernel<<<144, 256, 0, stream>>>(pw, Wb);
    attn_kernel<<<dim3(256, 8), 512, 0, stream>>>(Qs, Ks, Vs, AOs);
    proj_kernel<<<1536, 256, 0, stream>>>(AOs, Wb, pb, out);
}